// Round 1
// baseline (39.540 us; speedup 1.0000x reference)
//
#include <hip/hip_runtime.h>

// HashNGramEmbedding: out[b,s,:] = (1/6) * sum_k emb[k, h_k(b,s), :]
// h_k = rolling polynomial hash (base 257, mod 2^18) over trailing n-gram,
// n in {3,4,5,6,7,8}; positions s < n-1 fall back to the raw byte.

constexpr int HASH_VOCAB = 262144;            // 2^18
constexpr unsigned VMASK = HASH_VOCAB - 1;
constexpr int EMBED_DIM = 128;
constexpr int BATCH = 8;
constexpr int SEQ = 8192;
constexpr int NPOS = BATCH * SEQ;

__global__ __launch_bounds__(256) void hashngram_gather_kernel(
    const int* __restrict__ x, const float* __restrict__ emb,
    float* __restrict__ out) {
  const int tid = blockIdx.x * blockDim.x + threadIdx.x;
  const int pos = tid >> 5;            // global (b*SEQ + s)
  if (pos >= NPOS) return;
  const int s = pos & (SEQ - 1);       // position within sequence
  const int lane = tid & 31;           // column chunk (float4 index in row)

  // Trailing bytes x[pos], x[pos-1], ..., x[pos-7]; zero-pad before seq start.
  int bytes[8];
#pragma unroll
  for (int j = 0; j < 8; ++j) bytes[j] = (s >= j) ? x[pos - j] : 0;

  // Rolling hash chain shared across ngram sizes: state after j steps is the
  // hash for n = j+1. Fallback to raw byte when s < n-1 (== s < j).
  unsigned h[6];
  unsigned cur = (unsigned)bytes[0];
#pragma unroll
  for (int j = 1; j <= 7; ++j) {
    cur = (cur * 257u + (unsigned)bytes[j]) & VMASK;
    if (j >= 2) h[j - 2] = (s >= j) ? cur : (unsigned)bytes[0];
  }

  float4 acc = make_float4(0.f, 0.f, 0.f, 0.f);
#pragma unroll
  for (int k = 0; k < 6; ++k) {
    const float4* row = reinterpret_cast<const float4*>(
        emb + ((size_t)k * HASH_VOCAB + (size_t)h[k]) * EMBED_DIM);
    const float4 v = row[lane];
    acc.x += v.x; acc.y += v.y; acc.z += v.z; acc.w += v.w;
  }
  // Exact fp-order match with reference: accumulate k=0..5, then divide by 6.
  acc.x /= 6.0f; acc.y /= 6.0f; acc.z /= 6.0f; acc.w /= 6.0f;

  reinterpret_cast<float4*>(out)[tid] = acc;  // float4 idx == tid (coalesced)
}

extern "C" void kernel_launch(void* const* d_in, const int* in_sizes, int n_in,
                              void* d_out, int out_size, void* d_ws, size_t ws_size,
                              hipStream_t stream) {
  const int* x = (const int*)d_in[0];
  const float* emb = (const float*)d_in[1];
  float* out = (float*)d_out;

  const int total_threads = NPOS * 32;           // 2,097,152
  const int block = 256;
  const int grid = (total_threads + block - 1) / block;  // 8192
  hashngram_gather_kernel<<<grid, block, 0, stream>>>(x, emb, out);
}

// Round 3
// 39.330 us; speedup vs baseline: 1.0053x; 1.0053x over previous
//
#include <hip/hip_runtime.h>

// HashNGramEmbedding: out[b,s,:] = (1/6) * sum_k emb[k, h_k(b,s), :]
// h_k = rolling polynomial hash (base 257, mod 2^18) over trailing n-gram,
// n in {3,4,5,6,7,8}; positions s < n-1 fall back to the raw byte.
//
// R1: 39.54 us (~5.95 TB/s effective; ideal ~235 MB HBM traffic).
// R3: nontemporal output stores via native ext_vector float4 (HIP's float4
//     class type is rejected by __builtin_nontemporal_store) — keep the
//     33.6 MB write-once stream out of L2/LLC so the Infinity Cache retains
//     more of the 768 MiB table working set for gather hits.

constexpr int HASH_VOCAB = 262144;            // 2^18
constexpr unsigned VMASK = HASH_VOCAB - 1;
constexpr int EMBED_DIM = 128;
constexpr int BATCH = 8;
constexpr int SEQ = 8192;
constexpr int NPOS = BATCH * SEQ;

typedef float nfloat4 __attribute__((ext_vector_type(4)));

__global__ __launch_bounds__(256) void hashngram_gather_kernel(
    const int* __restrict__ x, const float* __restrict__ emb,
    float* __restrict__ out) {
  const int tid = blockIdx.x * blockDim.x + threadIdx.x;
  const int pos = tid >> 5;            // global (b*SEQ + s)
  if (pos >= NPOS) return;
  const int s = pos & (SEQ - 1);       // position within sequence
  const int lane = tid & 31;           // column chunk (float4 index in row)

  // Trailing bytes x[pos], x[pos-1], ..., x[pos-7]; zero-pad before seq start.
  int bytes[8];
#pragma unroll
  for (int j = 0; j < 8; ++j) bytes[j] = (s >= j) ? x[pos - j] : 0;

  // Rolling hash chain shared across ngram sizes: state after j steps is the
  // hash for n = j+1. Fallback to raw byte when s < n-1 (== s < j).
  unsigned h[6];
  unsigned cur = (unsigned)bytes[0];
#pragma unroll
  for (int j = 1; j <= 7; ++j) {
    cur = (cur * 257u + (unsigned)bytes[j]) & VMASK;
    if (j >= 2) h[j - 2] = (s >= j) ? cur : (unsigned)bytes[0];
  }

  nfloat4 acc = (nfloat4)(0.f);
#pragma unroll
  for (int k = 0; k < 6; ++k) {
    const nfloat4* row = reinterpret_cast<const nfloat4*>(
        emb + ((size_t)k * HASH_VOCAB + (size_t)h[k]) * EMBED_DIM);
    const nfloat4 v = row[lane];
    acc += v;
  }
  // Exact fp-order match with reference: accumulate k=0..5, then divide by 6.
  acc /= 6.0f;

  // Streaming store: output is write-once, never re-read -> bypass caches.
  __builtin_nontemporal_store(acc, reinterpret_cast<nfloat4*>(out) + tid);
}

extern "C" void kernel_launch(void* const* d_in, const int* in_sizes, int n_in,
                              void* d_out, int out_size, void* d_ws, size_t ws_size,
                              hipStream_t stream) {
  const int* x = (const int*)d_in[0];
  const float* emb = (const float*)d_in[1];
  float* out = (float*)d_out;

  const int total_threads = NPOS * 32;           // 2,097,152
  const int block = 256;
  const int grid = (total_threads + block - 1) / block;  // 8192
  hashngram_gather_kernel<<<grid, block, 0, stream>>>(x, emb, out);
}